// Round 1
// 204.712 us; speedup vs baseline: 1.0357x; 1.0357x over previous
//
#include <hip/hip_runtime.h>
#include <cstdint>
#include <cstddef>

typedef unsigned short u16;
typedef unsigned int   u32;
typedef unsigned long long u64;
typedef __attribute__((ext_vector_type(8))) short short8;   // 8 bf16 = 4 VGPR
typedef __attribute__((ext_vector_type(4))) float f32x4;

#define M_ROWS 16384
#define N_COLS 256
#define IN_F   1024
#define K_SPL  8192   // 1024 features * 8 basis
#define K_TOT  9216   // + 1024 base (silu) features
// BK=64 chunks: 144 total (128 spline chunks of 8 features, 16 base chunks of 64 feats)
#define NCHUNK 144
#define SPLITK 2
#define CPB    (NCHUNK / SPLITK)   // 72 chunks per block

// ---------- helpers ----------
__device__ __forceinline__ u32 f2bf1(float f) {          // f32 -> bf16 bits, RNE
  u32 u = __float_as_uint(f);
  u += 0x7fffu + ((u >> 16) & 1u);
  return u >> 16;
}
__device__ __forceinline__ u32 pk2(float a, float b) {
  return f2bf1(a) | (f2bf1(b) << 16);
}
__device__ __forceinline__ float silu(float v) {
  return v * __builtin_amdgcn_rcpf(1.f + __expf(-v));
}

// 8 bf16 cubic B-spline basis values for one x, packed as uint4 (16B).
// u = 2.5x + 5.5; basis_j(x) = N3(u - j); 4 nonzero wts scattered via funnel shift.
__device__ __forceinline__ uint4 basis8(float xv) {
  float u = fmaf(xv, 2.5f, 5.5f);
  int i0 = (int)u;
  float fr = u - (float)i0;
  float fr2 = fr * fr, fr3 = fr2 * fr;
  float om  = 1.f - fr;
  float om3 = om * om * om;
  float w0 = om3 * (1.f / 6.f);
  float w3 = fr3 * (1.f / 6.f);
  float w1 = fmaf(fr3, 0.5f, fmaf(fr2, -1.f, 2.f / 3.f));
  float w2 = fmaf(fr + fr2 - fr3, 0.5f, 1.f / 6.f);
  u64 W = (u64)pk2(w0, w1) | ((u64)pk2(w2, w3) << 32);
  if (!(u >= 0.f && u < 11.f)) W = 0ull;
  int s = (i0 - 3) * 16;
  u64 lo, hi;
  if (s >= 64)      { int r = s - 64; lo = 0ull; hi = (r < 64) ? (W << r) : 0ull; }
  else if (s > 0)   { lo = W << s;    hi = W >> (64 - s); }
  else if (s == 0)  { lo = W;         hi = 0ull; }
  else              { int r = -s;     lo = (r < 64) ? (W >> r) : 0ull; hi = 0ull; }
  uint4 o;
  o.x = (u32)lo; o.y = (u32)(lo >> 32); o.z = (u32)hi; o.w = (u32)(hi >> 32);
  return o;
}

// ---------- kernel 1: pack [spline_weight | base_weight] -> bf16, (256 x 9216) row-major ----------
__global__ void pack_weights(const float* __restrict__ bw, const float* __restrict__ sw,
                             u16* __restrict__ Bp) {
  int o  = blockIdx.y;
  int k4 = (blockIdx.x * blockDim.x + threadIdx.x) * 4;
  const float* src = (k4 < K_SPL) ? (sw + (size_t)o * K_SPL + k4)
                                  : (bw + (size_t)o * IN_F + (k4 - K_SPL));
  float a = src[0], b = src[1], c = src[2], d = src[3];
  uint2 v; v.x = pk2(a, b); v.y = pk2(c, d);
  *(uint2*)(Bp + (size_t)o * K_TOT + k4) = v;
}

// ---------- kernel 2: fused KAN GEMM ----------
// BM=64 BN=256(=N, full width!) BK=64; 512 thr = 8 waves of 32m x 64n (acc 2x4).
// split-K=2, kid = bid&1 (adjacent partner blocks; R1-proven: WRITE = 2x out).
// grid 512 -> 2 blocks/CU.
// NEW this round: double-buffered As/Bs (80 KB LDS, still 2 blocks/CU) with a
// SINGLE barrier per chunk. Next-chunk STAGEB (global_load_lds) + BUILD (VALU +
// ds_write) are issued BEFORE the current chunk's MFMA phase, so the vmcnt(0)
// drain at __syncthreads happens after ~16 MFMAs of cover instead of
// immediately (T3 "minimum 2-phase" recipe). Loop unrolled x2 for compile-time
// buffer indices.
// Each x element is loaded & basis-built exactly ONCE device-wide (BN covers all N).
// LDS 16B-chunk swizzle: chunk c of row r at slot r*8 + (c ^ (r&7)).
__global__ __launch_bounds__(512, 4)
void kan_gemm(const float* __restrict__ x, const u16* __restrict__ Bp,
              float* __restrict__ out) {
  __shared__ __align__(16) u16 Bs[2 * 256 * 64];   // 64 KB (2 bufs)
  __shared__ __align__(16) u16 As[2 * 64 * 64];    // 16 KB (2 bufs)

  const int tid  = threadIdx.x;
  const int lane = tid & 63;
  const int w    = tid >> 6;          // 0..7
  const int wm   = w & 1;             // m-half (32 rows)
  const int wn   = w >> 1;            // n-quarter (64 cols)

  const int bid  = blockIdx.x;        // 512
  const int kid  = bid & 1;
  const int mb   = bid >> 1;          // 0..255
  const int row0 = mb * 64;
  const int cs   = kid * CPB, c1 = cs + CPB;

  f32x4 acc[2][4];
#pragma unroll
  for (int i = 0; i < 2; ++i)
#pragma unroll
    for (int j = 0; j < 4; ++j)
      acc[i][j] = (f32x4){0.f, 0.f, 0.f, 0.f};

  const int sr = tid >> 3;            // staging row 0..63
  const int sq = tid & 7;             // feature (spline) / 8-feat group (base)

  // fragment read offsets (u16 index within one buffer), swizzled
  const int lm = lane & 15;
  const int kg = lane >> 4;
  int a_off[2][2], b_off[2][4];
#pragma unroll
  for (int h = 0; h < 2; ++h) {
    int c = h * 4 + kg;
#pragma unroll
    for (int i = 0; i < 2; ++i) {
      int ra = wm * 32 + i * 16 + lm;
      a_off[h][i] = ra * 64 + ((c ^ (ra & 7)) * 8);
    }
#pragma unroll
    for (int j = 0; j < 4; ++j) {
      int rb = wn * 64 + j * 16 + lm;
      b_off[h][j] = rb * 64 + ((c ^ (rb & 7)) * 8);
    }
  }

  float px;            // spline prefetch (1 feature/thread)
  float4 pb0, pb1;     // base prefetch (8 features/thread)

  auto LOADX = [&](int c) {
    if (c < 128) {
      px = x[(size_t)(row0 + sr) * IN_F + c * 8 + sq];
    } else {
      const float* xp = x + (size_t)(row0 + sr) * IN_F + (c - 128) * 64 + sq * 8;
      pb0 = *(const float4*)xp;
      pb1 = *(const float4*)(xp + 4);
    }
  };

  auto BUILD = [&](int c, int buf) {
    uint4 q;
    if (c < 128) {
      q = basis8(px);
    } else {
      q.x = pk2(silu(pb0.x), silu(pb0.y));
      q.y = pk2(silu(pb0.z), silu(pb0.w));
      q.z = pk2(silu(pb1.x), silu(pb1.y));
      q.w = pk2(silu(pb1.z), silu(pb1.w));
    }
    *(uint4*)(As + buf * (64 * 64) + sr * 64 + ((sq ^ (sr & 7)) * 8)) = q;
  };

  auto STAGEB = [&](int c, int buf) {
    u16* base = Bs + buf * (256 * 64);
#pragma unroll
    for (int it = 0; it < 4; ++it) {
      int s = tid + it * 512;
      int r_ = s >> 3, cc = (s & 7) ^ (r_ & 7);
      const u16* gp = Bp + (size_t)r_ * K_TOT + c * 64 + cc * 8;
      __builtin_amdgcn_global_load_lds((const __attribute__((address_space(1))) void*)gp,
                                       (__attribute__((address_space(3))) void*)(base + s * 8),
                                       16, 0, 0);
    }
  };

  auto MFMA_PHASE = [&](int buf) {
    const u16* Ab = As + buf * (64 * 64);
    const u16* Bb = Bs + buf * (256 * 64);
#pragma unroll
    for (int h = 0; h < 2; ++h) {
      short8 af[2], bf[4];
#pragma unroll
      for (int i = 0; i < 2; ++i) af[i] = *(const short8*)(Ab + a_off[h][i]);
#pragma unroll
      for (int j = 0; j < 4; ++j) bf[j] = *(const short8*)(Bb + b_off[h][j]);
#pragma unroll
      for (int i = 0; i < 2; ++i)
#pragma unroll
        for (int j = 0; j < 4; ++j)
          acc[i][j] = __builtin_amdgcn_mfma_f32_16x16x32_bf16(af[i], bf[j], acc[i][j], 0, 0, 0);
    }
  };

  // ---- prologue: chunk cs -> buf 0 ----
  LOADX(cs);
  STAGEB(cs, 0);
  BUILD(cs, 0);
  if (cs + 1 < c1) LOADX(cs + 1);
  __syncthreads();   // buf0 ready (vmcnt+lgkm drained)

  // ---- main loop: 1 barrier per chunk, x2 unrolled for static buffer idx ----
  // invariant at top of iter: buf0 holds chunk c, px holds x for chunk c+1
  for (int c = cs; c < c1; c += 2) {
    // chunk c on buf0; prefetch chunk c+1 -> buf1
    if (c + 1 < c1) { STAGEB(c + 1, 1); BUILD(c + 1, 1); }
    if (c + 2 < c1) LOADX(c + 2);
    MFMA_PHASE(0);
    __syncthreads();

    // chunk c+1 on buf1; prefetch chunk c+2 -> buf0
    if (c + 1 < c1) {
      if (c + 2 < c1) { STAGEB(c + 2, 0); BUILD(c + 2, 0); }
      if (c + 3 < c1) LOADX(c + 3);
      MFMA_PHASE(1);
      __syncthreads();
    }
  }

  // ---- epilogue: C/D layout col=lane&15, row=(lane>>4)*4+reg; split-K=2 -> atomic add ----
  const int lc = lane & 15;
  const int lr = (lane >> 4) * 4;
#pragma unroll
  for (int i = 0; i < 2; ++i) {
#pragma unroll
    for (int j = 0; j < 4; ++j) {
      int gr = row0 + wm * 32 + i * 16 + lr;
      int gc = wn * 64 + j * 16 + lc;
      float* po = out + (size_t)gr * N_COLS + gc;
#pragma unroll
      for (int r = 0; r < 4; ++r)
        unsafeAtomicAdd(po + (size_t)r * N_COLS, acc[i][j][r]);
    }
  }
}

extern "C" void kernel_launch(void* const* d_in, const int* in_sizes, int n_in,
                              void* d_out, int out_size, void* d_ws, size_t ws_size,
                              hipStream_t stream) {
  const float* x  = (const float*)d_in[0];   // 16384 x 1024
  const float* bw = (const float*)d_in[1];   // 256 x 1024
  const float* sw = (const float*)d_in[2];   // 256 x 8192
  float* out = (float*)d_out;                // 16384 x 256 f32
  u16* Bp = (u16*)d_ws;                      // 256 x 9216 bf16 = 4.5 MB

  hipMemsetAsync(d_out, 0, (size_t)M_ROWS * N_COLS * sizeof(float), stream);

  dim3 pgrid(K_TOT / 4 / 256, N_COLS);       // (9, 256)
  pack_weights<<<pgrid, 256, 0, stream>>>(bw, sw, Bp);

  kan_gemm<<<512, 512, 0, stream>>>(x, Bp, out);
}